// Round 1
// baseline (10955.814 us; speedup 1.0000x reference)
//
#include <hip/hip_runtime.h>

// EncoderRNN: bidirectional GRU, T=1024, B=64, H=256, V=32000, fp32.
// Layout of ws (float offsets):
//   wihT_f: 0        (256x768, [k][n])          196608 floats
//   wihT_b: 196608
//   whhP_f: 393216   packed float4 [g][k4][j]:  WhhP[g][k4][j][i] = Whh[g*256+j][4*k4+i]
//   whhP_b: 589824
//   hcar  : 786432   [dir][b][j]  2*64*256
//   xg    : 819200   two chunk buffers of Tc*64*768 each (f then b)

__device__ __forceinline__ float sigmoid_(float x) { return 1.0f / (1.0f + __expf(-x)); }
__device__ __forceinline__ float tanh_(float x)    { return 1.0f - 2.0f / (1.0f + __expf(2.0f * x)); }

__global__ __launch_bounds__(256) void prep_transpose(
    const float* __restrict__ wf, const float* __restrict__ wb,
    float* __restrict__ of, float* __restrict__ ob) {
  int idx = blockIdx.x * 256 + threadIdx.x;      // 0 .. 2*196608-1
  int d = idx / 196608;
  int r = idx - d * 196608;
  int k = r / 768, n = r - k * 768;
  const float* w = d ? wb : wf;
  float* o = d ? ob : of;
  o[r] = w[n * 256 + k];                         // WihT[k][n] = Wih[n][k]
}

__global__ __launch_bounds__(256) void prep_pack(
    const float* __restrict__ wf, const float* __restrict__ wb,
    float* __restrict__ of, float* __restrict__ ob) {
  int idx = blockIdx.x * 256 + threadIdx.x;      // 0 .. 2*49152-1 (float4 units)
  int d = idx / 49152;
  int r = idx - d * 49152;
  int j  = r & 255;
  int k4 = (r >> 8) & 63;
  int g  = r >> 14;
  const float* w = d ? wb : wf;
  float4* o = (float4*)(d ? ob : of);
  o[r] = *(const float4*)(w + ((size_t)(g * 256 + j) * 256 + 4 * k4));
}

// xg = gather(emb, seq) @ WihT + b_ih.  One block = one time step t, 64 batches x 64 cols.
__global__ __launch_bounds__(256) void xg_gemm(
    const int* __restrict__ seq, const int* __restrict__ lens,
    const float* __restrict__ emb,
    const float* __restrict__ wihT_f, const float* __restrict__ wihT_b,
    const float* __restrict__ bih_f, const float* __restrict__ bih_b,
    float* __restrict__ xg_f, float* __restrict__ xg_b,
    int base_f, int base_b) {
  const int tid = threadIdx.x;
  const int dir = blockIdx.z;
  const int sx  = blockIdx.y;                    // index within chunk
  const int t   = (dir ? base_b : base_f) + sx;
  const int n0  = blockIdx.x * 64;
  const float* wihT = dir ? wihT_b : wihT_f;
  const float* bih  = dir ? bih_b : bih_f;
  float* xg         = dir ? xg_b : xg_f;

  __shared__ __align__(16) float AsT[128 * 64];  // [k][m], staged in two K-halves
  __shared__ int tokS[64];
  __shared__ int lenS[64];
  if (tid < 64) tokS[tid] = seq[t * 64 + tid];
  else if (tid < 128) lenS[tid - 64] = lens[tid - 64];

  const int tx = tid & 15, ty = tid >> 4;        // col group / row group
  float acc[4][4];
#pragma unroll
  for (int i = 0; i < 4; ++i)
#pragma unroll
    for (int jj = 0; jj < 4; ++jj) acc[i][jj] = 0.0f;

  const int m_ld = tid >> 2, q_ld = tid & 3;

  for (int kh = 0; kh < 2; ++kh) {
    const int kk = kh * 128;
    __syncthreads();
    {
      const float* erow = emb + (size_t)tokS[m_ld] * 256 + kk + q_ld * 32;
#pragma unroll
      for (int i = 0; i < 8; ++i) {
        float4 v = *(const float4*)(erow + i * 4);
        int kb = q_ld * 32 + i * 4;
        AsT[(kb + 0) * 64 + m_ld] = v.x;
        AsT[(kb + 1) * 64 + m_ld] = v.y;
        AsT[(kb + 2) * 64 + m_ld] = v.z;
        AsT[(kb + 3) * 64 + m_ld] = v.w;
      }
    }
    __syncthreads();
    if (t < lenS[4 * ty]) {                      // lengths sorted desc -> max of this thread's 4 rows
#pragma unroll 4
      for (int k = 0; k < 128; ++k) {
        float4 a4 = *(const float4*)&AsT[k * 64 + 4 * ty];
        float4 b4 = *(const float4*)&wihT[(size_t)(kk + k) * 768 + n0 + 4 * tx];
        acc[0][0]=fmaf(a4.x,b4.x,acc[0][0]); acc[0][1]=fmaf(a4.x,b4.y,acc[0][1]); acc[0][2]=fmaf(a4.x,b4.z,acc[0][2]); acc[0][3]=fmaf(a4.x,b4.w,acc[0][3]);
        acc[1][0]=fmaf(a4.y,b4.x,acc[1][0]); acc[1][1]=fmaf(a4.y,b4.y,acc[1][1]); acc[1][2]=fmaf(a4.y,b4.z,acc[1][2]); acc[1][3]=fmaf(a4.y,b4.w,acc[1][3]);
        acc[2][0]=fmaf(a4.z,b4.x,acc[2][0]); acc[2][1]=fmaf(a4.z,b4.y,acc[2][1]); acc[2][2]=fmaf(a4.z,b4.z,acc[2][2]); acc[2][3]=fmaf(a4.z,b4.w,acc[2][3]);
        acc[3][0]=fmaf(a4.w,b4.x,acc[3][0]); acc[3][1]=fmaf(a4.w,b4.y,acc[3][1]); acc[3][2]=fmaf(a4.w,b4.z,acc[3][2]); acc[3][3]=fmaf(a4.w,b4.w,acc[3][3]);
      }
    }
  }
  float4 bias4 = *(const float4*)&bih[n0 + 4 * tx];
#pragma unroll
  for (int i = 0; i < 4; ++i) {
    int b = 4 * ty + i;
    if (t < lenS[b]) {
      float4 o;
      o.x = acc[i][0] + bias4.x; o.y = acc[i][1] + bias4.y;
      o.z = acc[i][2] + bias4.z; o.w = acc[i][3] + bias4.w;
      *(float4*)&xg[((size_t)sx * 64 + b) * 768 + n0 + 4 * tx] = o;
    }
  }
}

// Recurrent scan. One WG per (dir, batch-pair): 64 WGs. h lives in LDS.
__global__ __launch_bounds__(256) void gru_scan(
    const int* __restrict__ lens,
    const float* __restrict__ xg_f, const float* __restrict__ xg_b,
    const float* __restrict__ whhP_f, const float* __restrict__ whhP_b,
    const float* __restrict__ bhh_f, const float* __restrict__ bhh_b,
    float* __restrict__ out, float* __restrict__ hcar,
    int base_f, int base_b, int Tc, int is_last) {
  const int j   = threadIdx.x;
  const int dir = blockIdx.y;
  const int b0  = blockIdx.x * 2, b1 = b0 + 1;
  const float*  xg  = dir ? xg_b : xg_f;
  const float4* WP  = (const float4*)(dir ? whhP_b : whhP_f);
  const float*  bhh = dir ? bhh_b : bhh_f;
  float* hc = hcar + (size_t)dir * (64 * 256);
  const int len0 = lens[b0], len1 = lens[b1];
  const int lenmax = len0 > len1 ? len0 : len1;
  const int base = dir ? base_b : base_f;

  __shared__ __align__(16) float h[2][256];
  h[0][j] = hc[b0 * 256 + j];
  h[1][j] = hc[b1 * 256 + j];
  const float bhr = bhh[j], bhz = bhh[256 + j], bhn = bhh[512 + j];
  __syncthreads();

  int s_lo, s_hi;
  if (dir == 0) {                                // t = base + s, ascending
    s_lo = 0;
    int e = lenmax - base;
    s_hi = e < 0 ? 0 : (e > Tc ? Tc : e);
  } else {                                       // t = base + Tc-1-s, descending
    int sk = base + Tc - lenmax;
    s_lo = sk < 0 ? 0 : sk;
    s_hi = Tc;
  }

  const float4* wp0 = WP + j;
  const float4* h40 = (const float4*)h[0];
  const float4* h41 = (const float4*)h[1];

  for (int s = s_lo; s < s_hi; ++s) {
    const int t  = dir ? (base + (Tc - 1 - s)) : (base + s);
    const int sx = t - base;
    float ar0=0.f, az0=0.f, an0=0.f, ar1=0.f, az1=0.f, an1=0.f;
#pragma unroll 4
    for (int k4 = 0; k4 < 64; ++k4) {
      float4 wr = wp0[(size_t)k4 * 256];
      float4 wz = wp0[(size_t)(k4 + 64) * 256];
      float4 wn = wp0[(size_t)(k4 + 128) * 256];
      float4 h0 = h40[k4];
      float4 h1 = h41[k4];
      ar0=fmaf(wr.x,h0.x,ar0); ar0=fmaf(wr.y,h0.y,ar0); ar0=fmaf(wr.z,h0.z,ar0); ar0=fmaf(wr.w,h0.w,ar0);
      az0=fmaf(wz.x,h0.x,az0); az0=fmaf(wz.y,h0.y,az0); az0=fmaf(wz.z,h0.z,az0); az0=fmaf(wz.w,h0.w,az0);
      an0=fmaf(wn.x,h0.x,an0); an0=fmaf(wn.y,h0.y,an0); an0=fmaf(wn.z,h0.z,an0); an0=fmaf(wn.w,h0.w,an0);
      ar1=fmaf(wr.x,h1.x,ar1); ar1=fmaf(wr.y,h1.y,ar1); ar1=fmaf(wr.z,h1.z,ar1); ar1=fmaf(wr.w,h1.w,ar1);
      az1=fmaf(wz.x,h1.x,az1); az1=fmaf(wz.y,h1.y,az1); az1=fmaf(wz.z,h1.z,az1); az1=fmaf(wz.w,h1.w,az1);
      an1=fmaf(wn.x,h1.x,an1); an1=fmaf(wn.y,h1.y,an1); an1=fmaf(wn.z,h1.z,an1); an1=fmaf(wn.w,h1.w,an1);
    }
    const float* xrow0 = xg + ((size_t)sx * 64 + b0) * 768;
    const float* xrow1 = xrow0 + 768;
    float xr0 = xrow0[j], xz0 = xrow0[256 + j], xn0 = xrow0[512 + j];
    float xr1 = xrow1[j], xz1 = xrow1[256 + j], xn1 = xrow1[512 + j];

    float r0 = sigmoid_(xr0 + ar0 + bhr);
    float z0 = sigmoid_(xz0 + az0 + bhz);
    float nn0 = tanh_(xn0 + r0 * (an0 + bhn));
    float hn0 = (1.0f - z0) * nn0 + z0 * h[0][j];

    float r1 = sigmoid_(xr1 + ar1 + bhr);
    float z1 = sigmoid_(xz1 + az1 + bhz);
    float nn1 = tanh_(xn1 + r1 * (an1 + bhn));
    float hn1 = (1.0f - z1) * nn1 + z1 * h[1][j];

    const bool a0 = t < len0, a1 = t < len1;
    __syncthreads();                             // all k-loop reads of h done
    if (a0) { h[0][j] = hn0; out[((size_t)t * 64 + b0) * 256 + j] += hn0; }
    if (a1) { h[1][j] = hn1; out[((size_t)t * 64 + b1) * 256 + j] += hn1; }
    __syncthreads();                             // h updates visible before next step
  }

  hc[b0 * 256 + j] = h[0][j];
  hc[b1 * 256 + j] = h[1][j];
  if (is_last) {
    size_t hb = (size_t)1024 * 64 * 256 + (size_t)dir * 64 * 256;
    out[hb + b0 * 256 + j] = h[0][j];
    out[hb + b1 * 256 + j] = h[1][j];
  }
}

extern "C" void kernel_launch(void* const* d_in, const int* in_sizes, int n_in,
                              void* d_out, int out_size, void* d_ws, size_t ws_size,
                              hipStream_t stream) {
  const int*   seq   = (const int*)d_in[0];
  const int*   lens  = (const int*)d_in[1];
  const float* emb   = (const float*)d_in[2];
  const float* Wih_f = (const float*)d_in[3];
  const float* Whh_f = (const float*)d_in[4];
  const float* bih_f = (const float*)d_in[5];
  const float* bhh_f = (const float*)d_in[6];
  const float* Wih_b = (const float*)d_in[7];
  const float* Whh_b = (const float*)d_in[8];
  const float* bih_b = (const float*)d_in[9];
  const float* bhh_b = (const float*)d_in[10];
  float* out = (float*)d_out;
  float* ws  = (float*)d_ws;

  float* wihT_f = ws;
  float* wihT_b = ws + 196608;
  float* whhP_f = ws + 393216;
  float* whhP_b = ws + 589824;
  float* hcar   = ws + 786432;
  float* xgbase = ws + 819200;

  // Largest even-chunk-count Tc whose two xg chunk buffers fit in ws.
  int Tc = 8;
  const int cands[7] = {512, 256, 128, 64, 32, 16, 8};
  for (int i = 0; i < 7; ++i) {
    size_t need = (819200ull + 2ull * (size_t)cands[i] * 49152ull) * 4ull;
    if (need <= ws_size) { Tc = cands[i]; break; }
  }
  const int C = 1024 / Tc;                       // >= 2, power of two -> even
  float* xg_f = xgbase;
  float* xg_b = xgbase + (size_t)Tc * 49152;

  hipMemsetAsync(d_out, 0, (size_t)1024 * 64 * 256 * 4, stream);  // outputs region (both dirs +=)
  hipMemsetAsync(hcar, 0, (size_t)2 * 64 * 256 * 4, stream);      // initial h = 0
  prep_transpose<<<dim3(1536), dim3(256), 0, stream>>>(Wih_f, Wih_b, wihT_f, wihT_b);
  prep_pack<<<dim3(384), dim3(256), 0, stream>>>(Whh_f, Whh_b, whhP_f, whhP_b);

  for (int c = 0; c < C; ++c) {
    int base_f = c * Tc;
    int base_b = (C - 1 - c) * Tc;               // mirrored chunk for reverse scan
    xg_gemm<<<dim3(12, Tc, 2), dim3(256), 0, stream>>>(
        seq, lens, emb, wihT_f, wihT_b, bih_f, bih_b, xg_f, xg_b, base_f, base_b);
    gru_scan<<<dim3(32, 2), dim3(256), 0, stream>>>(
        lens, xg_f, xg_b, whhP_f, whhP_b, bhh_f, bhh_b, out, hcar,
        base_f, base_b, Tc, (c == C - 1) ? 1 : 0);
  }
}

// Round 2
// 7827.088 us; speedup vs baseline: 1.3997x; 1.3997x over previous
//
#include <hip/hip_runtime.h>

// EncoderRNN: bidirectional GRU, T=1024, B=64, H=256, V=32000, fp32.
// ws layout (float offsets):
//   wihT_f: 0        (256x768, [k][n])          196608 floats
//   wihT_b: 196608
//   whhP_f: 393216   packed float4 [g][kq][i][j]: WP[((g*4+kq)*16+i)*256+j] = Whh[g*256+j][kq*64+i*4 ..+3]
//   whhP_b: 589824
//   hcar  : 786432   [dir][b][j]  2*64*256
//   xg    : 819200   two chunk buffers of Tc*64*768 each (f then b)

__device__ __forceinline__ float sigmoid_(float x) { return 1.0f / (1.0f + __expf(-x)); }
__device__ __forceinline__ float tanh_(float x)    { return 1.0f - 2.0f / (1.0f + __expf(2.0f * x)); }

__global__ __launch_bounds__(256) void prep_transpose(
    const float* __restrict__ wf, const float* __restrict__ wb,
    float* __restrict__ of, float* __restrict__ ob) {
  int idx = blockIdx.x * 256 + threadIdx.x;      // 0 .. 2*196608-1
  int d = idx / 196608;
  int r = idx - d * 196608;
  int k = r / 768, n = r - k * 768;
  const float* w = d ? wb : wf;
  float* o = d ? ob : of;
  o[r] = w[n * 256 + k];                         // WihT[k][n] = Wih[n][k]
}

// Pack Whh so the scan's wave (fixed kq, consecutive j) loads contiguous 1KB.
__global__ __launch_bounds__(256) void prep_pack(
    const float* __restrict__ wf, const float* __restrict__ wb,
    float* __restrict__ of, float* __restrict__ ob) {
  int idx = blockIdx.x * 256 + threadIdx.x;      // 0 .. 2*49152-1 (float4 units)
  int d = idx / 49152;
  int r = idx - d * 49152;
  int j  = r & 255;
  int t1 = r >> 8;
  int i  = t1 & 15;
  int t2 = t1 >> 4;
  int kq = t2 & 3;
  int g  = t2 >> 2;
  const float* w = d ? wb : wf;
  float4* o = (float4*)(d ? ob : of);
  o[r] = *(const float4*)(w + ((size_t)(g * 256 + j) * 256 + kq * 64 + i * 4));
}

// xg = gather(emb, seq) @ WihT + b_ih.  One block = one time step t, 64 batches x 64 cols.
__global__ __launch_bounds__(256) void xg_gemm(
    const int* __restrict__ seq, const int* __restrict__ lens,
    const float* __restrict__ emb,
    const float* __restrict__ wihT_f, const float* __restrict__ wihT_b,
    const float* __restrict__ bih_f, const float* __restrict__ bih_b,
    float* __restrict__ xg_f, float* __restrict__ xg_b,
    int base_f, int base_b) {
  const int tid = threadIdx.x;
  const int dir = blockIdx.z;
  const int sx  = blockIdx.y;                    // index within chunk
  const int t   = (dir ? base_b : base_f) + sx;
  const int n0  = blockIdx.x * 64;
  const float* wihT = dir ? wihT_b : wihT_f;
  const float* bih  = dir ? bih_b : bih_f;
  float* xg         = dir ? xg_b : xg_f;

  __shared__ __align__(16) float AsT[128 * 64];  // [k][m], staged in two K-halves
  __shared__ int tokS[64];
  __shared__ int lenS[64];
  if (tid < 64) tokS[tid] = seq[t * 64 + tid];
  else if (tid < 128) lenS[tid - 64] = lens[tid - 64];

  const int tx = tid & 15, ty = tid >> 4;        // col group / row group
  float acc[4][4];
#pragma unroll
  for (int i = 0; i < 4; ++i)
#pragma unroll
    for (int jj = 0; jj < 4; ++jj) acc[i][jj] = 0.0f;

  const int m_ld = tid >> 2, q_ld = tid & 3;

  for (int kh = 0; kh < 2; ++kh) {
    const int kk = kh * 128;
    __syncthreads();
    {
      const float* erow = emb + (size_t)tokS[m_ld] * 256 + kk + q_ld * 32;
#pragma unroll
      for (int i = 0; i < 8; ++i) {
        float4 v = *(const float4*)(erow + i * 4);
        int kb = q_ld * 32 + i * 4;
        AsT[(kb + 0) * 64 + m_ld] = v.x;
        AsT[(kb + 1) * 64 + m_ld] = v.y;
        AsT[(kb + 2) * 64 + m_ld] = v.z;
        AsT[(kb + 3) * 64 + m_ld] = v.w;
      }
    }
    __syncthreads();
    if (t < lenS[4 * ty]) {                      // lengths sorted desc -> max of this thread's 4 rows
#pragma unroll 4
      for (int k = 0; k < 128; ++k) {
        float4 a4 = *(const float4*)&AsT[k * 64 + 4 * ty];
        float4 b4 = *(const float4*)&wihT[(size_t)(kk + k) * 768 + n0 + 4 * tx];
        acc[0][0]=fmaf(a4.x,b4.x,acc[0][0]); acc[0][1]=fmaf(a4.x,b4.y,acc[0][1]); acc[0][2]=fmaf(a4.x,b4.z,acc[0][2]); acc[0][3]=fmaf(a4.x,b4.w,acc[0][3]);
        acc[1][0]=fmaf(a4.y,b4.x,acc[1][0]); acc[1][1]=fmaf(a4.y,b4.y,acc[1][1]); acc[1][2]=fmaf(a4.y,b4.z,acc[1][2]); acc[1][3]=fmaf(a4.y,b4.w,acc[1][3]);
        acc[2][0]=fmaf(a4.z,b4.x,acc[2][0]); acc[2][1]=fmaf(a4.z,b4.y,acc[2][1]); acc[2][2]=fmaf(a4.z,b4.z,acc[2][2]); acc[2][3]=fmaf(a4.z,b4.w,acc[2][3]);
        acc[3][0]=fmaf(a4.w,b4.x,acc[3][0]); acc[3][1]=fmaf(a4.w,b4.y,acc[3][1]); acc[3][2]=fmaf(a4.w,b4.z,acc[3][2]); acc[3][3]=fmaf(a4.w,b4.w,acc[3][3]);
      }
    }
  }
  float4 bias4 = *(const float4*)&bih[n0 + 4 * tx];
#pragma unroll
  for (int i = 0; i < 4; ++i) {
    int b = 4 * ty + i;
    if (t < lenS[b]) {
      float4 o;
      o.x = acc[i][0] + bias4.x; o.y = acc[i][1] + bias4.y;
      o.z = acc[i][2] + bias4.z; o.w = acc[i][3] + bias4.w;
      *(float4*)&xg[((size_t)sx * 64 + b) * 768 + n0 + 4 * tx] = o;
    }
  }
}

// Recurrent scan, k-split 4-way. 1024 threads: thread=(j=tid&255, kq=tid>>8).
// One WG per (dir, batch-pair): 64 WGs, 16 waves/CU.
__global__ __launch_bounds__(1024) void gru_scan(
    const int* __restrict__ lens,
    const float* __restrict__ xg_f, const float* __restrict__ xg_b,
    const float* __restrict__ whhP_f, const float* __restrict__ whhP_b,
    const float* __restrict__ bhh_f, const float* __restrict__ bhh_b,
    float* __restrict__ out, float* __restrict__ hcar,
    int base_f, int base_b, int Tc, int is_last, int do_add) {
  const int tid = threadIdx.x;
  const int j   = tid & 255;
  const int kq  = tid >> 8;                      // 0..3 (k-range kq*64..+63)
  const int dir = blockIdx.y;
  const int b0  = blockIdx.x * 2;
  const float4* WP  = (const float4*)(dir ? whhP_b : whhP_f);
  const float*  xg  = dir ? xg_b : xg_f;
  const float*  bhh = dir ? bhh_b : bhh_f;
  float* hc = hcar + (size_t)dir * (64 * 256);
  const int len0 = lens[b0], len1 = lens[b0 + 1];
  const int lenmax = len0 > len1 ? len0 : len1;
  const int base = dir ? base_b : base_f;

  __shared__ __align__(16) float h[2][256];
  __shared__ float part[2 * 3 * 4 * 256];        // [(b*3+g)*4+kq][j]  24KB

  const int eb   = kq & 1;                       // epilogue batch (valid when tid<512)
  const int bb   = b0 + eb;
  const int blen = eb ? len1 : len0;
  if (tid < 512) h[eb][j] = hc[bb * 256 + j];
  float bhr = 0.f, bhz = 0.f, bhn = 0.f;
  if (tid < 512) { bhr = bhh[j]; bhz = bhh[256 + j]; bhn = bhh[512 + j]; }
  __syncthreads();

  int s_lo, s_hi;
  if (dir == 0) {                                // t = base + s
    s_lo = 0;
    int e = lenmax - base;
    s_hi = e < 0 ? 0 : (e > Tc ? Tc : e);
  } else {                                       // t = base + Tc-1-s
    int sk = base + Tc - lenmax;
    s_lo = sk < 0 ? 0 : sk;
    s_hi = Tc;
  }

  const float4* wp  = WP + kq * 4096 + j;        // [g=0][kq][i=0][j]
  const float4* h40 = ((const float4*)h[0]) + kq * 16;
  const float4* h41 = ((const float4*)h[1]) + kq * 16;

  for (int s = s_lo; s < s_hi; ++s) {
    const int t  = dir ? (base + (Tc - 1 - s)) : (base + s);
    const int sx = t - base;
    const bool act = (tid < 512) && (t < blen);

    // Prefetch epilogue operands early; latency hidden under the matvec.
    float oprev = 0.f, xr = 0.f, xz = 0.f, xn = 0.f;
    if (tid < 512) {
      const float* xrow = xg + ((size_t)sx * 64 + bb) * 768;
      xr = xrow[j]; xz = xrow[256 + j]; xn = xrow[512 + j];
      if (do_add && act) oprev = out[((size_t)t * 64 + bb) * 256 + j];
    }

    float ar0=0.f, az0=0.f, an0=0.f, ar1=0.f, az1=0.f, an1=0.f;
#pragma unroll 4
    for (int i = 0; i < 16; ++i) {
      float4 wr = wp[i * 256];
      float4 wz = wp[16384 + i * 256];
      float4 wn = wp[32768 + i * 256];
      float4 ha = h40[i];                        // wave-uniform broadcast
      float4 hb = h41[i];
      ar0=fmaf(wr.x,ha.x,ar0); ar0=fmaf(wr.y,ha.y,ar0); ar0=fmaf(wr.z,ha.z,ar0); ar0=fmaf(wr.w,ha.w,ar0);
      az0=fmaf(wz.x,ha.x,az0); az0=fmaf(wz.y,ha.y,az0); az0=fmaf(wz.z,ha.z,az0); az0=fmaf(wz.w,ha.w,az0);
      an0=fmaf(wn.x,ha.x,an0); an0=fmaf(wn.y,ha.y,an0); an0=fmaf(wn.z,ha.z,an0); an0=fmaf(wn.w,ha.w,an0);
      ar1=fmaf(wr.x,hb.x,ar1); ar1=fmaf(wr.y,hb.y,ar1); ar1=fmaf(wr.z,hb.z,ar1); ar1=fmaf(wr.w,hb.w,ar1);
      az1=fmaf(wz.x,hb.x,az1); az1=fmaf(wz.y,hb.y,az1); az1=fmaf(wz.z,hb.z,az1); az1=fmaf(wz.w,hb.w,az1);
      an1=fmaf(wn.x,hb.x,an1); an1=fmaf(wn.y,hb.y,an1); an1=fmaf(wn.z,hb.z,an1); an1=fmaf(wn.w,hb.w,an1);
    }
    part[(0  + kq) * 256 + j] = ar0;             // (b0,g0)
    part[(4  + kq) * 256 + j] = az0;             // (b0,g1)
    part[(8  + kq) * 256 + j] = an0;             // (b0,g2)
    part[(12 + kq) * 256 + j] = ar1;             // (b1,g0)
    part[(16 + kq) * 256 + j] = az1;             // (b1,g1)
    part[(20 + kq) * 256 + j] = an1;             // (b1,g2)
    __syncthreads();

    if (tid < 512) {
      const int pb = eb * 12;
      float ar = part[(pb + 0) * 256 + j] + part[(pb + 1) * 256 + j]
               + part[(pb + 2) * 256 + j] + part[(pb + 3) * 256 + j];
      float az = part[(pb + 4) * 256 + j] + part[(pb + 5) * 256 + j]
               + part[(pb + 6) * 256 + j] + part[(pb + 7) * 256 + j];
      float an = part[(pb + 8) * 256 + j] + part[(pb + 9) * 256 + j]
               + part[(pb + 10) * 256 + j] + part[(pb + 11) * 256 + j];
      float r  = sigmoid_(xr + ar + bhr);
      float z  = sigmoid_(xz + az + bhz);
      float nn = tanh_(xn + r * (an + bhn));
      float hn = (1.0f - z) * nn + z * h[eb][j];
      if (act) {
        h[eb][j] = hn;
        out[((size_t)t * 64 + bb) * 256 + j] = do_add ? (oprev + hn) : hn;
      }
    }
    __syncthreads();
  }

  if (tid < 512) {
    hc[bb * 256 + j] = h[eb][j];
    if (is_last) {
      size_t hb = (size_t)1024 * 64 * 256 + (size_t)dir * 64 * 256;
      out[hb + bb * 256 + j] = h[eb][j];
    }
  }
}

extern "C" void kernel_launch(void* const* d_in, const int* in_sizes, int n_in,
                              void* d_out, int out_size, void* d_ws, size_t ws_size,
                              hipStream_t stream) {
  const int*   seq   = (const int*)d_in[0];
  const int*   lens  = (const int*)d_in[1];
  const float* emb   = (const float*)d_in[2];
  const float* Wih_f = (const float*)d_in[3];
  const float* Whh_f = (const float*)d_in[4];
  const float* bih_f = (const float*)d_in[5];
  const float* bhh_f = (const float*)d_in[6];
  const float* Wih_b = (const float*)d_in[7];
  const float* Whh_b = (const float*)d_in[8];
  const float* bih_b = (const float*)d_in[9];
  const float* bhh_b = (const float*)d_in[10];
  float* out = (float*)d_out;
  float* ws  = (float*)d_ws;

  float* wihT_f = ws;
  float* wihT_b = ws + 196608;
  float* whhP_f = ws + 393216;
  float* whhP_b = ws + 589824;
  float* hcar   = ws + 786432;
  float* xgbase = ws + 819200;

  // Largest Tc whose two xg chunk buffers fit in ws (C = 1024/Tc even).
  int Tc = 8;
  const int cands[7] = {512, 256, 128, 64, 32, 16, 8};
  for (int i = 0; i < 7; ++i) {
    size_t need = (819200ull + 2ull * (size_t)cands[i] * 49152ull) * 4ull;
    if (need <= ws_size) { Tc = cands[i]; break; }
  }
  const int C = 1024 / Tc;
  float* xg_f = xgbase;
  float* xg_b = xgbase + (size_t)Tc * 49152;

  hipMemsetAsync(d_out, 0, (size_t)1024 * 64 * 256 * 4, stream);  // masked outputs stay 0
  hipMemsetAsync(hcar, 0, (size_t)2 * 64 * 256 * 4, stream);      // initial h = 0
  prep_transpose<<<dim3(1536), dim3(256), 0, stream>>>(Wih_f, Wih_b, wihT_f, wihT_b);
  prep_pack<<<dim3(384), dim3(256), 0, stream>>>(Whh_f, Whh_b, whhP_f, whhP_b);

  for (int c = 0; c < C; ++c) {
    int base_f = c * Tc;
    int base_b = (C - 1 - c) * Tc;               // mirrored chunk for reverse scan
    int do_add = (2 * c >= C) ? 1 : 0;           // second writer at a given t adds
    xg_gemm<<<dim3(12, Tc, 2), dim3(256), 0, stream>>>(
        seq, lens, emb, wihT_f, wihT_b, bih_f, bih_b, xg_f, xg_b, base_f, base_b);
    gru_scan<<<dim3(32, 2), dim3(1024), 0, stream>>>(
        lens, xg_f, xg_b, whhP_f, whhP_b, bhh_f, bhh_b, out, hcar,
        base_f, base_b, Tc, (c == C - 1) ? 1 : 0, do_add);
  }
}

// Round 3
// 4504.997 us; speedup vs baseline: 2.4319x; 1.7374x over previous
//
#include <hip/hip_runtime.h>

// EncoderRNN: bidirectional GRU, T=1024, B=64, H=256, V=32000, fp32.
// Round 3: persistent-weights scan. Whh lives in VGPRs (64 floats/thread),
// h exchanged between 4 peer WGs per (dir, batch-pair) via coherence-point
// (agent-scope) atomics with a double-buffered h and monotone step flags.
//
// ws layout (float offsets):
//   wihT_f: 0        (256x768, [k][n])          196608 floats
//   wihT_b: 196608
//   hbuf  : 393216   [par 2][dir 2][b 64][j 256] = 65536 floats
//   flags : 458752   4096 uints (one per WG, padded x16)
//   xg    : 462848   two chunk buffers of Tc*64*768 each (f then b)

#define SCOPE_AGENT __HIP_MEMORY_SCOPE_AGENT

__device__ __forceinline__ float sigmoid_(float x) { return 1.0f / (1.0f + __expf(-x)); }
__device__ __forceinline__ float tanh_(float x)    { return 1.0f - 2.0f / (1.0f + __expf(2.0f * x)); }

__global__ __launch_bounds__(256) void prep_transpose(
    const float* __restrict__ wf, const float* __restrict__ wb,
    float* __restrict__ of, float* __restrict__ ob) {
  int idx = blockIdx.x * 256 + threadIdx.x;      // 0 .. 2*196608-1
  int d = idx / 196608;
  int r = idx - d * 196608;
  int k = r / 768, n = r - k * 768;
  const float* w = d ? wb : wf;
  float* o = d ? ob : of;
  o[r] = w[n * 256 + k];                         // WihT[k][n] = Wih[n][k]
}

// xg = gather(emb, seq) @ WihT + b_ih.  One block = one time step t, 64 batches x 64 cols.
__global__ __launch_bounds__(256) void xg_gemm(
    const int* __restrict__ seq, const int* __restrict__ lens,
    const float* __restrict__ emb,
    const float* __restrict__ wihT_f, const float* __restrict__ wihT_b,
    const float* __restrict__ bih_f, const float* __restrict__ bih_b,
    float* __restrict__ xg_f, float* __restrict__ xg_b,
    int base_f, int base_b) {
  const int tid = threadIdx.x;
  const int dir = blockIdx.z;
  const int sx  = blockIdx.y;                    // index within chunk
  const int t   = (dir ? base_b : base_f) + sx;
  const int n0  = blockIdx.x * 64;
  const float* wihT = dir ? wihT_b : wihT_f;
  const float* bih  = dir ? bih_b : bih_f;
  float* xg         = dir ? xg_b : xg_f;

  __shared__ __align__(16) float AsT[128 * 64];  // [k][m], staged in two K-halves
  __shared__ int tokS[64];
  __shared__ int lenS[64];
  if (tid < 64) tokS[tid] = seq[t * 64 + tid];
  else if (tid < 128) lenS[tid - 64] = lens[tid - 64];

  const int tx = tid & 15, ty = tid >> 4;
  float acc[4][4];
#pragma unroll
  for (int i = 0; i < 4; ++i)
#pragma unroll
    for (int jj = 0; jj < 4; ++jj) acc[i][jj] = 0.0f;

  const int m_ld = tid >> 2, q_ld = tid & 3;

  for (int kh = 0; kh < 2; ++kh) {
    const int kk = kh * 128;
    __syncthreads();
    {
      const float* erow = emb + (size_t)tokS[m_ld] * 256 + kk + q_ld * 32;
#pragma unroll
      for (int i = 0; i < 8; ++i) {
        float4 v = *(const float4*)(erow + i * 4);
        int kb = q_ld * 32 + i * 4;
        AsT[(kb + 0) * 64 + m_ld] = v.x;
        AsT[(kb + 1) * 64 + m_ld] = v.y;
        AsT[(kb + 2) * 64 + m_ld] = v.z;
        AsT[(kb + 3) * 64 + m_ld] = v.w;
      }
    }
    __syncthreads();
    if (t < lenS[4 * ty]) {
#pragma unroll 4
      for (int k = 0; k < 128; ++k) {
        float4 a4 = *(const float4*)&AsT[k * 64 + 4 * ty];
        float4 b4 = *(const float4*)&wihT[(size_t)(kk + k) * 768 + n0 + 4 * tx];
        acc[0][0]=fmaf(a4.x,b4.x,acc[0][0]); acc[0][1]=fmaf(a4.x,b4.y,acc[0][1]); acc[0][2]=fmaf(a4.x,b4.z,acc[0][2]); acc[0][3]=fmaf(a4.x,b4.w,acc[0][3]);
        acc[1][0]=fmaf(a4.y,b4.x,acc[1][0]); acc[1][1]=fmaf(a4.y,b4.y,acc[1][1]); acc[1][2]=fmaf(a4.y,b4.z,acc[1][2]); acc[1][3]=fmaf(a4.y,b4.w,acc[1][3]);
        acc[2][0]=fmaf(a4.z,b4.x,acc[2][0]); acc[2][1]=fmaf(a4.z,b4.y,acc[2][1]); acc[2][2]=fmaf(a4.z,b4.z,acc[2][2]); acc[2][3]=fmaf(a4.z,b4.w,acc[2][3]);
        acc[3][0]=fmaf(a4.w,b4.x,acc[3][0]); acc[3][1]=fmaf(a4.w,b4.y,acc[3][1]); acc[3][2]=fmaf(a4.w,b4.z,acc[3][2]); acc[3][3]=fmaf(a4.w,b4.w,acc[3][3]);
      }
    }
  }
  float4 bias4 = *(const float4*)&bih[n0 + 4 * tx];
#pragma unroll
  for (int i = 0; i < 4; ++i) {
    int b = 4 * ty + i;
    if (t < lenS[b]) {
      float4 o;
      o.x = acc[i][0] + bias4.x; o.y = acc[i][1] + bias4.y;
      o.z = acc[i][2] + bias4.z; o.w = acc[i][3] + bias4.w;
      *(float4*)&xg[((size_t)sx * 64 + b) * 768 + n0 + 4 * tx] = o;
    }
  }
}

// Persistent-weights recurrent scan.
// Grid 256 WGs x 768 threads. gid = g + 64*p, g = dir*32+q (sync group), p = j-slice.
// Thread (rp = tid%96, k8 = tid/96) holds Whh rows {2rp, 2rp+1} (local), k-slice k8*32..+31
// in 16 float4 VGPRs. Per step: FMA -> LDS k-reduce -> epilogue(128 thr) -> publish.
__global__ __launch_bounds__(768, 3) void gru_scan(
    const int* __restrict__ lens,
    const float* __restrict__ xg_f, const float* __restrict__ xg_b,
    const float* __restrict__ Whh_f, const float* __restrict__ Whh_b,
    const float* __restrict__ bhh_f, const float* __restrict__ bhh_b,
    float* __restrict__ out, float* hbuf, unsigned int* flags,
    int base_f, int base_b, int Tc, int c, int C, int is_last, int do_add) {
  const int tid = threadIdx.x;
  const int gid = blockIdx.x;
  const int g   = gid & 63;                      // sync group (dir,q); peers share XCD (g%8)
  const int p   = gid >> 6;                      // peer 0..3
  const int dir = g >> 5;
  const int q   = g & 31;
  const int b0  = q * 2;
  const int j0  = p * 64;

  const float* xg  = dir ? xg_b : xg_f;
  const float* Wd  = dir ? Whh_b : Whh_f;
  const float* bhh = dir ? bhh_b : bhh_f;
  const int len0 = lens[b0], len1 = lens[b0 + 1];
  const int lenmax = len0 > len1 ? len0 : len1;
  const int base = dir ? base_b : base_f;

  const int k8 = tid / 96;                       // 0..7
  const int rp = tid - k8 * 96;                  // 0..95 (row pair)
  // load resident weights: global row0 = gate*256 + j0 + 2q, row1 = row0+1
  const int row0 = (rp >> 5) * 256 + j0 + 2 * (rp & 31);
  float4 w0[8], w1[8];
  {
    const float* wr = Wd + (size_t)row0 * 256 + k8 * 32;
#pragma unroll
    for (int i = 0; i < 8; ++i) {
      w0[i] = *(const float4*)(wr + 4 * i);
      w1[i] = *(const float4*)(wr + 256 + 4 * i);
    }
  }
  const int lrow0 = 2 * rp;                      // local row (gate*64 + jl)

  __shared__ __align__(16) float hlds[2][256];
  __shared__ float part[16][192];                // [b*8+k8][local row]

  const int ej = tid & 63, eb2 = (tid >> 6) & 1; // epilogue role (tid<128)
  float bhr = 0.f, bhz = 0.f, bhn = 0.f;
  if (tid < 128) { bhr = bhh[j0 + ej]; bhz = bhh[256 + j0 + ej]; bhn = bhh[512 + j0 + ej]; }

  int s_lo, s_hi;
  if (dir == 0) { s_lo = 0; int e = lenmax - base; s_hi = e < 0 ? 0 : (e > Tc ? Tc : e); }
  else { int sk = base + Tc - lenmax; s_lo = sk < 0 ? 0 : (sk > Tc ? Tc : sk); s_hi = Tc; }

  // exchanges completed in previous chunks (identical across peers)
  int cnt = 0;
  for (int cc = 0; cc < c; ++cc) {
    int bx = dir ? (C - 1 - cc) * Tc : cc * Tc;
    int lo, hi;
    if (dir == 0) { lo = 0; int e = lenmax - bx; hi = e < 0 ? 0 : (e > Tc ? Tc : e); }
    else { int sk = bx + Tc - lenmax; lo = sk < 0 ? 0 : (sk > Tc ? Tc : sk); hi = Tc; }
    cnt += hi - lo;
  }

  float* hb_base = hbuf + (size_t)dir * 64 * 256;  // + parity*2*64*256
  unsigned int* myflag = flags + gid * 16;

  for (int s = s_lo; s < s_hi; ++s) {
    const int t  = dir ? (base + (Tc - 1 - s)) : (base + s);
    const int sx = t - base;

    // prefetch epilogue inputs (independent of h; hides under poll+matvec)
    float xr = 0.f, xz = 0.f, xn = 0.f, oprev = 0.f;
    bool act = false; int bb = 0;
    if (tid < 128) {
      bb = b0 + eb2;
      const int blen = eb2 ? len1 : len0;
      act = t < blen;
      const float* xrow = xg + ((size_t)sx * 64 + bb) * 768 + j0 + ej;
      xr = xrow[0]; xz = xrow[256]; xn = xrow[512];
      if (do_add && act) oprev = out[((size_t)t * 64 + bb) * 256 + j0 + ej];
    }

    // wait: all 4 peers have published h_cnt
    if (tid < 4) {
      const unsigned int* pf = flags + (g + (tid << 6)) * 16;
      while (__hip_atomic_load(pf, __ATOMIC_ACQUIRE, SCOPE_AGENT) < (unsigned)cnt) {
        __builtin_amdgcn_s_sleep(1);
      }
    }
    __syncthreads();

    // stage h_cnt from coherence point into LDS
    const float* hsrc = hb_base + (size_t)(cnt & 1) * 2 * 64 * 256;
    if (tid < 512) {
      int b = tid >> 8, jj = tid & 255;
      hlds[b][jj] = __hip_atomic_load(hsrc + (b0 + b) * 256 + jj, __ATOMIC_RELAXED, SCOPE_AGENT);
    }
    __syncthreads();

    // matvec: 2 rows x 2 batches per thread over k-slice (weights in VGPRs)
    float a00 = 0.f, a01 = 0.f, a10 = 0.f, a11 = 0.f;
    const float4* h0v = (const float4*)&hlds[0][k8 * 32];
    const float4* h1v = (const float4*)&hlds[1][k8 * 32];
#pragma unroll
    for (int i = 0; i < 8; ++i) {
      float4 hv0 = h0v[i], hv1 = h1v[i];
      a00=fmaf(w0[i].x,hv0.x,a00); a00=fmaf(w0[i].y,hv0.y,a00); a00=fmaf(w0[i].z,hv0.z,a00); a00=fmaf(w0[i].w,hv0.w,a00);
      a01=fmaf(w0[i].x,hv1.x,a01); a01=fmaf(w0[i].y,hv1.y,a01); a01=fmaf(w0[i].z,hv1.z,a01); a01=fmaf(w0[i].w,hv1.w,a01);
      a10=fmaf(w1[i].x,hv0.x,a10); a10=fmaf(w1[i].y,hv0.y,a10); a10=fmaf(w1[i].z,hv0.z,a10); a10=fmaf(w1[i].w,hv0.w,a10);
      a11=fmaf(w1[i].x,hv1.x,a11); a11=fmaf(w1[i].y,hv1.y,a11); a11=fmaf(w1[i].z,hv1.z,a11); a11=fmaf(w1[i].w,hv1.w,a11);
    }
    part[k8][lrow0]       = a00;
    part[k8][lrow0 + 1]   = a10;
    part[8 + k8][lrow0]     = a01;
    part[8 + k8][lrow0 + 1] = a11;
    __syncthreads();

    // epilogue: 128 threads = (j in slice, batch)
    if (tid < 128) {
      float ar = 0.f, az = 0.f, an = 0.f;
#pragma unroll
      for (int kk = 0; kk < 8; ++kk) {
        ar += part[eb2 * 8 + kk][ej];
        az += part[eb2 * 8 + kk][64 + ej];
        an += part[eb2 * 8 + kk][128 + ej];
      }
      float r  = sigmoid_(xr + ar + bhr);
      float z  = sigmoid_(xz + az + bhz);
      float nn = tanh_(xn + r * (an + bhn));
      float hold = hlds[eb2][j0 + ej];
      float hn = act ? ((1.0f - z) * nn + z * hold) : hold;  // masked: carry h
      float* hdst = hb_base + (size_t)((cnt + 1) & 1) * 2 * 64 * 256 + (size_t)bb * 256 + j0 + ej;
      __hip_atomic_store(hdst, hn, __ATOMIC_RELAXED, SCOPE_AGENT);
      if (act) out[((size_t)t * 64 + bb) * 256 + j0 + ej] = do_add ? (oprev + hn) : hn;
    }
    __syncthreads();                             // each wave drains vmcnt before barrier
    if (tid == 0)
      __hip_atomic_store(myflag, (unsigned)(cnt + 1), __ATOMIC_RELEASE, SCOPE_AGENT);
    ++cnt;
  }

  if (is_last) {                                 // final hidden: own slice only
    if (tid < 512) {
      int b = tid >> 8, jj = tid & 255;
      if ((jj >> 6) == p) {
        const float* hsrc = hb_base + (size_t)(cnt & 1) * 2 * 64 * 256;
        float hv = __hip_atomic_load(hsrc + (b0 + b) * 256 + jj, __ATOMIC_RELAXED, SCOPE_AGENT);
        out[(size_t)1024 * 64 * 256 + (size_t)dir * 64 * 256 + (b0 + b) * 256 + jj] = hv;
      }
    }
  }
}

extern "C" void kernel_launch(void* const* d_in, const int* in_sizes, int n_in,
                              void* d_out, int out_size, void* d_ws, size_t ws_size,
                              hipStream_t stream) {
  const int*   seq   = (const int*)d_in[0];
  const int*   lens  = (const int*)d_in[1];
  const float* emb   = (const float*)d_in[2];
  const float* Wih_f = (const float*)d_in[3];
  const float* Whh_f = (const float*)d_in[4];
  const float* bih_f = (const float*)d_in[5];
  const float* bhh_f = (const float*)d_in[6];
  const float* Wih_b = (const float*)d_in[7];
  const float* Whh_b = (const float*)d_in[8];
  const float* bih_b = (const float*)d_in[9];
  const float* bhh_b = (const float*)d_in[10];
  float* out = (float*)d_out;
  float* ws  = (float*)d_ws;

  float*        wihT_f = ws;
  float*        wihT_b = ws + 196608;
  float*        hbuf   = ws + 393216;
  unsigned int* flags  = (unsigned int*)(ws + 458752);
  float*        xgbase = ws + 462848;

  // Largest Tc whose two xg chunk buffers fit in ws (C = 1024/Tc even).
  int Tc = 8;
  const int cands[7] = {512, 256, 128, 64, 32, 16, 8};
  for (int i = 0; i < 7; ++i) {
    size_t need = (462848ull + 2ull * (size_t)cands[i] * 49152ull) * 4ull;
    if (need <= ws_size) { Tc = cands[i]; break; }
  }
  const int C = 1024 / Tc;
  float* xg_f = xgbase;
  float* xg_b = xgbase + (size_t)Tc * 49152;

  hipMemsetAsync(d_out, 0, (size_t)1024 * 64 * 256 * 4, stream);        // masked outputs stay 0
  hipMemsetAsync(hbuf, 0, (65536ull + 4096ull) * 4ull, stream);         // h=0 (both parities) + flags=0
  prep_transpose<<<dim3(1536), dim3(256), 0, stream>>>(Wih_f, Wih_b, wihT_f, wihT_b);

  for (int c = 0; c < C; ++c) {
    int base_f = c * Tc;
    int base_b = (C - 1 - c) * Tc;               // mirrored chunk for reverse scan
    int do_add = (2 * c >= C) ? 1 : 0;           // second writer at a given t adds
    xg_gemm<<<dim3(12, Tc, 2), dim3(256), 0, stream>>>(
        seq, lens, emb, wihT_f, wihT_b, bih_f, bih_b, xg_f, xg_b, base_f, base_b);
    gru_scan<<<dim3(256), dim3(768), 0, stream>>>(
        lens, xg_f, xg_b, Whh_f, Whh_b, bhh_f, bhh_b, out, hbuf, flags,
        base_f, base_b, Tc, c, C, (c == C - 1) ? 1 : 0, do_add);
  }
}

// Round 4
// 2373.346 us; speedup vs baseline: 4.6162x; 1.8982x over previous
//
#include <hip/hip_runtime.h>

// EncoderRNN: bidirectional GRU, T=1024, B=64, H=256, V=32000, fp32.
// Round 4: persistent-bf16-MFMA scan. Whh (bf16) lives in VGPRs as MFMA
// A-fragments (384 KB/dir fits one CU's 512 KB VGPR file). One WG per
// (dir, batch-pair) -> NO cross-WG sync. h carried fp32 in registers;
// bf16 copy in LDS feeds B-fragments each step.
//
// ws layout (float offsets):
//   wihT_f: 0        (256x768, [k][n])          196608 floats
//   wihT_b: 196608
//   hcar  : 393216   [dir][b][j]  2*64*256 = 32768 floats
//   pA    : 425984   bf16 A-frags, 2*196608 ushorts = 196608 float-slots
//   xg    : 622592   two chunk buffers of Tc*64*768 each (f then b)

typedef __attribute__((ext_vector_type(8))) short short8;    // 8 bf16 (4 VGPRs)
typedef __attribute__((ext_vector_type(4))) float floatx4;   // 4 fp32 (acc)

__device__ __forceinline__ float sigmoid_(float x) { return 1.0f / (1.0f + __expf(-x)); }
__device__ __forceinline__ float tanh_(float x)    { return 1.0f - 2.0f / (1.0f + __expf(2.0f * x)); }
__device__ __forceinline__ unsigned short f2bf(float f) {     // RNE fp32->bf16
  unsigned int u = __float_as_uint(f);
  return (unsigned short)((u + 0x7fffu + ((u >> 16) & 1u)) >> 16);
}

__global__ __launch_bounds__(256) void prep_transpose(
    const float* __restrict__ wf, const float* __restrict__ wb,
    float* __restrict__ of, float* __restrict__ ob) {
  int idx = blockIdx.x * 256 + threadIdx.x;      // 0 .. 2*196608-1
  int d = idx / 196608;
  int r = idx - d * 196608;
  int k = r / 768, n = r - k * 768;
  const float* w = d ? wb : wf;
  float* o = d ? ob : of;
  o[r] = w[n * 256 + k];                         // WihT[k][n] = Wih[n][k]
}

// Pack Whh into bf16 MFMA A-fragments.
// pA[dir][tile(48)][kc(8)][lane(64)][j(8)]: A[m=lane&15][k=(lane>>4)*8+j]
// for row = tile*16+m, k = kc*32 + (lane>>4)*8 + j.
__global__ __launch_bounds__(256) void prep_packA(
    const float* __restrict__ wf, const float* __restrict__ wb,
    unsigned short* __restrict__ oA) {
  int idx = blockIdx.x * 256 + threadIdx.x;      // 0 .. 2*196608-1
  int d = idx / 196608;
  int o = idx - d * 196608;
  int jj   = o & 7;
  int lane = (o >> 3) & 63;
  int kc   = (o >> 9) & 7;
  int tl   = o >> 12;                            // 0..47
  int row  = tl * 16 + (lane & 15);
  int k    = kc * 32 + (lane >> 4) * 8 + jj;
  const float* w = d ? wb : wf;
  oA[idx] = f2bf(w[row * 256 + k]);
}

// xg = gather(emb, seq) @ WihT + b_ih.  One block = one time step t, 64 batches x 64 cols.
__global__ __launch_bounds__(256) void xg_gemm(
    const int* __restrict__ seq, const int* __restrict__ lens,
    const float* __restrict__ emb,
    const float* __restrict__ wihT_f, const float* __restrict__ wihT_b,
    const float* __restrict__ bih_f, const float* __restrict__ bih_b,
    float* __restrict__ xg_f, float* __restrict__ xg_b,
    int base_f, int base_b) {
  const int tid = threadIdx.x;
  const int dir = blockIdx.z;
  const int sx  = blockIdx.y;                    // index within chunk
  const int t   = (dir ? base_b : base_f) + sx;
  const int n0  = blockIdx.x * 64;
  const float* wihT = dir ? wihT_b : wihT_f;
  const float* bih  = dir ? bih_b : bih_f;
  float* xg         = dir ? xg_b : xg_f;

  __shared__ __align__(16) float AsT[128 * 64];  // [k][m], staged in two K-halves
  __shared__ int tokS[64];
  __shared__ int lenS[64];
  if (tid < 64) tokS[tid] = seq[t * 64 + tid];
  else if (tid < 128) lenS[tid - 64] = lens[tid - 64];

  const int tx = tid & 15, ty = tid >> 4;
  float acc[4][4];
#pragma unroll
  for (int i = 0; i < 4; ++i)
#pragma unroll
    for (int jj = 0; jj < 4; ++jj) acc[i][jj] = 0.0f;

  const int m_ld = tid >> 2, q_ld = tid & 3;

  for (int kh = 0; kh < 2; ++kh) {
    const int kk = kh * 128;
    __syncthreads();
    {
      const float* erow = emb + (size_t)tokS[m_ld] * 256 + kk + q_ld * 32;
#pragma unroll
      for (int i = 0; i < 8; ++i) {
        float4 v = *(const float4*)(erow + i * 4);
        int kb = q_ld * 32 + i * 4;
        AsT[(kb + 0) * 64 + m_ld] = v.x;
        AsT[(kb + 1) * 64 + m_ld] = v.y;
        AsT[(kb + 2) * 64 + m_ld] = v.z;
        AsT[(kb + 3) * 64 + m_ld] = v.w;
      }
    }
    __syncthreads();
    if (t < lenS[4 * ty]) {
#pragma unroll 4
      for (int k = 0; k < 128; ++k) {
        float4 a4 = *(const float4*)&AsT[k * 64 + 4 * ty];
        float4 b4 = *(const float4*)&wihT[(size_t)(kk + k) * 768 + n0 + 4 * tx];
        acc[0][0]=fmaf(a4.x,b4.x,acc[0][0]); acc[0][1]=fmaf(a4.x,b4.y,acc[0][1]); acc[0][2]=fmaf(a4.x,b4.z,acc[0][2]); acc[0][3]=fmaf(a4.x,b4.w,acc[0][3]);
        acc[1][0]=fmaf(a4.y,b4.x,acc[1][0]); acc[1][1]=fmaf(a4.y,b4.y,acc[1][1]); acc[1][2]=fmaf(a4.y,b4.z,acc[1][2]); acc[1][3]=fmaf(a4.y,b4.w,acc[1][3]);
        acc[2][0]=fmaf(a4.z,b4.x,acc[2][0]); acc[2][1]=fmaf(a4.z,b4.y,acc[2][1]); acc[2][2]=fmaf(a4.z,b4.z,acc[2][2]); acc[2][3]=fmaf(a4.z,b4.w,acc[2][3]);
        acc[3][0]=fmaf(a4.w,b4.x,acc[3][0]); acc[3][1]=fmaf(a4.w,b4.y,acc[3][1]); acc[3][2]=fmaf(a4.w,b4.z,acc[3][2]); acc[3][3]=fmaf(a4.w,b4.w,acc[3][3]);
      }
    }
  }
  float4 bias4 = *(const float4*)&bih[n0 + 4 * tx];
#pragma unroll
  for (int i = 0; i < 4; ++i) {
    int b = 4 * ty + i;
    if (t < lenS[b]) {
      float4 o;
      o.x = acc[i][0] + bias4.x; o.y = acc[i][1] + bias4.y;
      o.z = acc[i][2] + bias4.z; o.w = acc[i][3] + bias4.w;
      *(float4*)&xg[((size_t)sx * 64 + b) * 768 + n0 + 4 * tx] = o;
    }
  }
}

// Persistent-bf16-MFMA recurrent scan. Grid (32 pairs, 2 dirs) x 512 threads.
// Wave w holds tiles 6w..6w+5 (16 rows x 256 k each) as A-frags in VGPRs.
// Per step: hbf(LDS) -> B-frags -> 48 MFMA/wave -> res(LDS) -> epilogue.
__global__ __launch_bounds__(512, 2) void gru_scan(
    const int* __restrict__ lens,
    const float* __restrict__ xg_f, const float* __restrict__ xg_b,
    const unsigned short* __restrict__ pA,
    const float* __restrict__ bhh_f, const float* __restrict__ bhh_b,
    float* __restrict__ out, float* __restrict__ hcar,
    int base_f, int base_b, int Tc, int is_last, int do_add) {
  const int tid  = threadIdx.x;
  const int lane = tid & 63;
  const int wv   = tid >> 6;                     // 0..7
  const int qp   = blockIdx.x;                   // batch pair
  const int dir  = blockIdx.y;
  const int b0   = qp * 2;

  const float* xg  = dir ? xg_b : xg_f;
  const float* bhh = dir ? bhh_b : bhh_f;
  const int len0 = lens[b0], len1 = lens[b0 + 1];
  const int lenmax = len0 > len1 ? len0 : len1;
  const int base = dir ? base_b : base_f;

  // Resident A-fragments: 6 tiles x 8 k-chunks x 4 VGPRs = 192 VGPRs.
  short8 af[6][8];
  {
    const short8* pA8 = (const short8*)(pA + (size_t)dir * 196608);
#pragma unroll
    for (int i = 0; i < 6; ++i)
#pragma unroll
      for (int kc = 0; kc < 8; ++kc)
        af[i][kc] = pA8[(((wv * 6 + i) * 8 + kc) << 6) + lane];
  }

  __shared__ __align__(16) unsigned short hbf[2 * 288];  // stride 288 ush = 144 dw (=16 mod 32)
  __shared__ __align__(16) float res[2 * 784];           // stride 784 dw (=16 mod 32, mult of 4)

  // Epilogue role: thread = (b = tid>>8, j = tid&255); h fp32 lives here.
  const int b  = tid >> 8;
  const int j  = tid & 255;
  const int bb = b0 + b;
  const int blen = b ? len1 : len0;
  float hreg = hcar[dir * 16384 + bb * 256 + j];
  const float bhr = bhh[j], bhz = bhh[256 + j], bhn = bhh[512 + j];
  hbf[b * 288 + j] = f2bf(hreg);
  __syncthreads();

  int s_lo, s_hi;
  if (dir == 0) { s_lo = 0; int e = lenmax - base; s_hi = e < 0 ? 0 : (e > Tc ? Tc : e); }
  else { int sk = base + Tc - lenmax; s_lo = sk < 0 ? 0 : (sk > Tc ? Tc : sk); s_hi = Tc; }

  const int nB = lane & 15, qq = lane >> 4;
  const bool bld = nB < 2;                       // 8 lanes/wave carry B data
  const unsigned short* hsrc = &hbf[nB * 288 + qq * 8];

  for (int s = s_lo; s < s_hi; ++s) {
    const int t  = dir ? (base + (Tc - 1 - s)) : (base + s);
    const int sx = t - base;
    const bool act = t < blen;

    // prefetch epilogue operands (independent of h; hides under MFMA)
    const float* xrow = xg + ((size_t)sx * 64 + bb) * 768 + j;
    float xr = xrow[0], xz = xrow[256], xn = xrow[512];
    float oprev = 0.f;
    if (do_add && act) oprev = out[((size_t)t * 64 + bb) * 256 + j];

    floatx4 acc[6];
#pragma unroll
    for (int i = 0; i < 6; ++i) acc[i] = (floatx4){0.f, 0.f, 0.f, 0.f};

#pragma unroll
    for (int kc = 0; kc < 8; ++kc) {
      short8 bfr = {0, 0, 0, 0, 0, 0, 0, 0};
      if (bld) bfr = *(const short8*)(hsrc + kc * 32);  // conflict-free masked b128
#pragma unroll
      for (int i = 0; i < 6; ++i)
        acc[i] = __builtin_amdgcn_mfma_f32_16x16x32_bf16(af[i][kc], bfr, acc[i], 0, 0, 0);
    }

    // extract: D col = lane&15 (batch), row = (lane>>4)*4 + reg  [m89-verified]
    if (bld) {
#pragma unroll
      for (int i = 0; i < 6; ++i) {
        int r0 = (wv * 6 + i) * 16 + qq * 4;
        *(floatx4*)&res[nB * 784 + r0] = acc[i];
      }
    }
    __syncthreads();

    // epilogue: all 512 threads
    float ar = res[b * 784 + j];
    float az = res[b * 784 + 256 + j];
    float an = res[b * 784 + 512 + j];
    float r  = sigmoid_(xr + ar + bhr);
    float z  = sigmoid_(xz + az + bhz);
    float nn = tanh_(xn + r * (an + bhn));
    float hn = (1.0f - z) * nn + z * hreg;
    if (act) {
      hreg = hn;
      hbf[b * 288 + j] = f2bf(hn);
      out[((size_t)t * 64 + bb) * 256 + j] = do_add ? (oprev + hn) : hn;
    }
    __syncthreads();                             // hbf/res consistent for next step
  }

  hcar[dir * 16384 + bb * 256 + j] = hreg;
  if (is_last)
    out[(size_t)1024 * 64 * 256 + (size_t)dir * 16384 + bb * 256 + j] = hreg;
}

extern "C" void kernel_launch(void* const* d_in, const int* in_sizes, int n_in,
                              void* d_out, int out_size, void* d_ws, size_t ws_size,
                              hipStream_t stream) {
  const int*   seq   = (const int*)d_in[0];
  const int*   lens  = (const int*)d_in[1];
  const float* emb   = (const float*)d_in[2];
  const float* Wih_f = (const float*)d_in[3];
  const float* Whh_f = (const float*)d_in[4];
  const float* bih_f = (const float*)d_in[5];
  const float* bhh_f = (const float*)d_in[6];
  const float* Wih_b = (const float*)d_in[7];
  const float* Whh_b = (const float*)d_in[8];
  const float* bih_b = (const float*)d_in[9];
  const float* bhh_b = (const float*)d_in[10];
  float* out = (float*)d_out;
  float* ws  = (float*)d_ws;

  float*          wihT_f = ws;
  float*          wihT_b = ws + 196608;
  float*          hcar   = ws + 393216;
  unsigned short* pA     = (unsigned short*)(ws + 425984);
  float*          xgbase = ws + 622592;

  // Largest Tc whose two xg chunk buffers fit in ws (C = 1024/Tc even).
  int Tc = 8;
  const int cands[7] = {512, 256, 128, 64, 32, 16, 8};
  for (int i = 0; i < 7; ++i) {
    size_t need = (622592ull + 2ull * (size_t)cands[i] * 49152ull) * 4ull;
    if (need <= ws_size) { Tc = cands[i]; break; }
  }
  const int C = 1024 / Tc;
  float* xg_f = xgbase;
  float* xg_b = xgbase + (size_t)Tc * 49152;

  hipMemsetAsync(d_out, 0, (size_t)1024 * 64 * 256 * 4, stream);  // masked outputs stay 0
  hipMemsetAsync(hcar, 0, 32768ull * 4ull, stream);               // initial h = 0
  prep_transpose<<<dim3(1536), dim3(256), 0, stream>>>(Wih_f, Wih_b, wihT_f, wihT_b);
  prep_packA<<<dim3(1536), dim3(256), 0, stream>>>(Whh_f, Whh_b, pA);

  for (int c = 0; c < C; ++c) {
    int base_f = c * Tc;
    int base_b = (C - 1 - c) * Tc;               // mirrored chunk for reverse scan
    int do_add = (2 * c >= C) ? 1 : 0;           // second writer at a given t adds
    xg_gemm<<<dim3(12, Tc, 2), dim3(256), 0, stream>>>(
        seq, lens, emb, wihT_f, wihT_b, bih_f, bih_b, xg_f, xg_b, base_f, base_b);
    gru_scan<<<dim3(32, 2), dim3(512), 0, stream>>>(
        lens, xg_f, xg_b, pA, bhh_f, bhh_b, out, hcar,
        base_f, base_b, Tc, (c == C - 1) ? 1 : 0, do_add);
  }
}